// Round 9
// baseline (26518.494 us; speedup 1.0000x reference)
//
#include <hip/hip_runtime.h>
#include <math.h>

#define D 128
#define NLAYER 16
#define V 17
#define L 1024
#define BOSX 16
#define NWG 256
#define NT 1024

struct P {
  const int* tokens;
  const float *emb, *pos, *ln1_s, *ln1_b, *wqkv, *bqkv, *wo, *bo;
  const float *ln2_s, *ln2_b, *w1, *b1, *w2, *b2, *lnf_s, *lnf_b, *hw, *hb;
  float *kc, *vc, *ll_;
  int *lat, *heal_row, *barc, *done, *heals_done;
  float *logits, *out_tok;
};

// ---- uncached (coherence-point) accessors ----
__device__ __forceinline__ void stUf(float* p, float v) {
  __hip_atomic_store(p, v, __ATOMIC_RELAXED, __HIP_MEMORY_SCOPE_SYSTEM);
}
__device__ __forceinline__ int ldUi(const int* p) {
  return __hip_atomic_load((int*)p, __ATOMIC_RELAXED, __HIP_MEMORY_SCOPE_SYSTEM);
}
__device__ __forceinline__ void stUi(int* p, int v) {
  __hip_atomic_store(p, v, __ATOMIC_RELAXED, __HIP_MEMORY_SCOPE_SYSTEM);
}

// ---- full barrier (phase A + transitions): wb/inv fence, relaxed spin ----
__device__ __forceinline__ void barFull(int* cnt, int& b) {
  asm volatile("s_waitcnt vmcnt(0)" ::: "memory");
  __syncthreads();
  if (threadIdx.x == 0) {
    __threadfence();
    __hip_atomic_fetch_add(cnt, 1, __ATOMIC_RELAXED, __HIP_MEMORY_SCOPE_AGENT);
    int tgt = (b + 1) * NWG;
    while (__hip_atomic_load(cnt, __ATOMIC_RELAXED, __HIP_MEMORY_SCOPE_AGENT) < tgt)
      __builtin_amdgcn_s_sleep(8);
    __threadfence();
  }
  b += 1;
  __syncthreads();
}

__device__ __forceinline__ float geluf(float a) {
  float cgv = 0.7978845608028654f * (a + 0.044715f * a * a * a);
  cgv = fminf(fmaxf(cgv, -15.f), 15.f);
  float e = __expf(2.f * cgv);
  return 0.5f * a * (1.f + (e - 1.f) / (e + 1.f));
}

// LayerNorm in[0..127]->out[0..127]; 1024 threads (only t<128 compute)
__device__ void lnorm(const float* __restrict__ s, const float* __restrict__ b,
                      const float* in, float* out, float* red) {
  int t = threadIdx.x;
  float v = (t < D) ? in[t] : 0.f;
  float sm = v;
#pragma unroll
  for (int o = 32; o; o >>= 1) sm += __shfl_xor(sm, o, 64);
  if (t < D && (t & 63) == 0) red[t >> 6] = sm;
  __syncthreads();
  float mean = (red[0] + red[1]) * (1.f / 128.f);
  float d = (t < D) ? (v - mean) : 0.f;
  float vs = d * d;
#pragma unroll
  for (int o = 32; o; o >>= 1) vs += __shfl_xor(vs, o, 64);
  if (t < D && (t & 63) == 0) red[2 + (t >> 6)] = vs;
  __syncthreads();
  float rstd = rsqrtf((red[2] + red[3]) * (1.f / 128.f) + 1e-5f);
  if (t < D) out[t] = d * rstd * s[t] + b[t];
  __syncthreads();
}

// QKV: x[128] @ w[128x384] + b. 8 segs x 96 col-quads (float4). q->LDS, K/V->global.
template <bool HEAL>
__device__ void qkvPub(const P& p, int l, int row, int split, const float* x,
                       float* qrow, float* padS) {
  int t = threadIdx.x;
  int cg = t & 127, seg = t >> 7;  // 8 segs x 16 d's; cg<96 active
  if (cg < 96) {
    const float* w = p.wqkv + (size_t)l * D * 384;
    float4 acc = {0.f, 0.f, 0.f, 0.f};
    int d0 = seg * 16;
#pragma unroll
    for (int d = d0; d < d0 + 16; ++d) {
      float4 wv = *(const float4*)(w + (size_t)d * 384 + cg * 4);
      float xv = x[d];
      acc.x += xv * wv.x; acc.y += xv * wv.y; acc.z += xv * wv.z; acc.w += xv * wv.w;
    }
    *(float4*)&padS[seg * 384 + cg * 4] = acc;
  }
  __syncthreads();
  if (t < 384) {
    float a = padS[t] + padS[384 + t] + padS[768 + t] + padS[1152 + t]
            + padS[1536 + t] + padS[1920 + t] + padS[2304 + t] + padS[2688 + t]
            + p.bqkv[l * 384 + t];
    float* kcl = p.kc + (size_t)l * L * D + (size_t)row * D;
    float* vcl = p.vc + (size_t)l * L * D + (size_t)row * D;
    if (t < 128) qrow[t] = a;
    else if (t < 256) { if (HEAL) stUf(&kcl[t - 128], a); else kcl[t - 128] = a; }
    else              { if (HEAL) stUf(&vcl[t - 256], a); else vcl[t - 256] = a; }
  }
  if (HEAL) {
    asm volatile("s_waitcnt vmcnt(0)" ::: "memory");
    __syncthreads();
    if (t == 0) {
      int* dl = p.done + l * L;
      if (row - 1 >= split)
        while (ldUi(&dl[row - 1]) < 1) __builtin_amdgcn_s_sleep(1);
      stUi(&dl[row], 1);
    }
    __syncthreads();
  } else {
    __syncthreads();
  }
}

// attention(l)+proj+res+LN2+FF1+FF2+res for one row; 1024 threads.
__device__ void attnProjFFN(const P& p, int row, int l,
                            float* hrow, const float* qrow,
                            float* oS, float* xnS, float* fS, float* padS, float* redS) {
  int t = threadIdx.x;
  const float* kcl = p.kc + (size_t)l * L * D;
  const float* vcl = p.vc + (size_t)l * L * D;
  // ---- attn: 16 heads x 64 lanes ----
  {
    int head = t >> 6, lane = t & 63;
    const float* qh = qrow + head * 8;
    float q0=qh[0],q1=qh[1],q2=qh[2],q3=qh[3],q4=qh[4],q5=qh[5],q6=qh[6],q7=qh[7];
    float sum = 0.f, a0=0,a1=0,a2=0,a3=0,a4=0,a5=0,a6=0,a7=0;
#pragma unroll 2
    for (int key = lane; key <= row; key += 64) {
      const float4* kp = (const float4*)(kcl + (size_t)key * D + head * 8);
      float4 k0 = kp[0], k1 = kp[1];
      float sc = q0*k0.x+q1*k0.y+q2*k0.z+q3*k0.w+q4*k1.x+q5*k1.y+q6*k1.z+q7*k1.w;
      float pr = __expf(sc * 0.35355339059327376f);
      const float4* vp = (const float4*)(vcl + (size_t)key * D + head * 8);
      float4 v0 = vp[0], v1 = vp[1];
      sum += pr;
      a0+=pr*v0.x; a1+=pr*v0.y; a2+=pr*v0.z; a3+=pr*v0.w;
      a4+=pr*v1.x; a5+=pr*v1.y; a6+=pr*v1.z; a7+=pr*v1.w;
    }
#pragma unroll
    for (int o = 1; o < 64; o <<= 1) {
      sum += __shfl_xor(sum, o, 64);
      a0 += __shfl_xor(a0, o, 64); a1 += __shfl_xor(a1, o, 64);
      a2 += __shfl_xor(a2, o, 64); a3 += __shfl_xor(a3, o, 64);
      a4 += __shfl_xor(a4, o, 64); a5 += __shfl_xor(a5, o, 64);
      a6 += __shfl_xor(a6, o, 64); a7 += __shfl_xor(a7, o, 64);
    }
    if (lane == 0) {
      float inv = 1.f / sum;
      oS[head*8+0]=a0*inv; oS[head*8+1]=a1*inv; oS[head*8+2]=a2*inv; oS[head*8+3]=a3*inv;
      oS[head*8+4]=a4*inv; oS[head*8+5]=a5*inv; oS[head*8+6]=a6*inv; oS[head*8+7]=a7*inv;
    }
  }
  __syncthreads();
  // ---- proj: 32 segs(4 d) x 32 col-quads ----
  {
    int cg = t & 31, seg = t >> 5;
    const float* wp = p.wo + (size_t)l * D * D;
    float4 acc = {0.f, 0.f, 0.f, 0.f};
    int d0 = seg * 4;
#pragma unroll
    for (int d = d0; d < d0 + 4; ++d) {
      float4 wv = *(const float4*)(wp + (size_t)d * 128 + cg * 4);
      float ov = oS[d];
      acc.x += ov * wv.x; acc.y += ov * wv.y; acc.z += ov * wv.z; acc.w += ov * wv.w;
    }
    *(float4*)&padS[seg * 128 + cg * 4] = acc;
  }
  __syncthreads();
  if (t < D) {
    float a = 0.f;
#pragma unroll
    for (int s = 0; s < 32; ++s) a += padS[s * 128 + t];
    hrow[t] += a + p.bo[l * D + t];
  }
  __syncthreads();
  lnorm(p.ln2_s + l * D, p.ln2_b + l * D, hrow, xnS, redS);
  // ---- FF1: 8 segs(16 d) x 128 col-quads ----
  {
    int cg = t & 127, seg = t >> 7;
    const float* w1p = p.w1 + (size_t)l * D * 512;
    float4 acc = {0.f, 0.f, 0.f, 0.f};
    int d0 = seg * 16;
#pragma unroll
    for (int d = d0; d < d0 + 16; ++d) {
      float4 wv = *(const float4*)(w1p + (size_t)d * 512 + cg * 4);
      float xv = xnS[d];
      acc.x += xv * wv.x; acc.y += xv * wv.y; acc.z += xv * wv.z; acc.w += xv * wv.w;
    }
    *(float4*)&padS[seg * 512 + cg * 4] = acc;
  }
  __syncthreads();
  if (t < 512) {
    float a = padS[t] + padS[512 + t] + padS[1024 + t] + padS[1536 + t]
            + padS[2048 + t] + padS[2560 + t] + padS[3072 + t] + padS[3584 + t];
    fS[t] = geluf(a + p.b1[l * 512 + t]);
  }
  __syncthreads();
  // ---- FF2: 32 segs(16 d) x 32 col-quads ----
  {
    int cg = t & 31, seg = t >> 5;
    const float* w2p = p.w2 + (size_t)l * 512 * D;
    float4 acc = {0.f, 0.f, 0.f, 0.f};
    int d0 = seg * 16;
#pragma unroll
    for (int d = d0; d < d0 + 16; ++d) {
      float4 wv = *(const float4*)(w2p + (size_t)d * 128 + cg * 4);
      float fv = fS[d];
      acc.x += fv * wv.x; acc.y += fv * wv.y; acc.z += fv * wv.z; acc.w += fv * wv.w;
    }
    *(float4*)&padS[seg * 128 + cg * 4] = acc;
  }
  __syncthreads();
  if (t < D) {
    float a = 0.f;
#pragma unroll
    for (int s = 0; s < 32; ++s) a += padS[s * 128 + t];
    hrow[t] += a + p.b2[l * D + t];
  }
  __syncthreads();
}

// LNf + head; logits -> global (+ oS for argmax)
template <bool HEAL>
__device__ void headRow(const P& p, int row, float* hrow,
                        float* xnS, float* redS, float* padS, float* oS) {
  lnorm(p.lnf_s, p.lnf_b, hrow, xnS, redS);
  int t = threadIdx.x;
  if (t < V * 32) {
    int col = t >> 5, seg = t & 31;
    float acc = 0.f;
    int d0 = seg * 4;
#pragma unroll
    for (int d = d0; d < d0 + 4; ++d) acc += xnS[d] * p.hw[d * V + col];
    padS[col * 32 + seg] = acc;
  }
  __syncthreads();
  if (t < V) {
    float a = p.hb[t];
#pragma unroll
    for (int s = 0; s < 32; ++s) a += padS[t * 32 + s];
    oS[t] = a;
    if (HEAL) stUf(&p.logits[row * V + t], a);
    else      p.logits[row * V + t] = a;
  }
  __syncthreads();
}

// ---- init: lat + flags, all uncached ----
__global__ void kInit(const int* __restrict__ tokens, int* __restrict__ lat,
                      int* __restrict__ barc, int* __restrict__ done,
                      int* __restrict__ hd) {
  int i = blockIdx.x * blockDim.x + threadIdx.x;
  if (i == 0) stUi(lat, BOSX);
  if (i < L) stUi(lat + i + 1, tokens[i]);
  if (i < 64) stUi(barc + i, 0);
  if (i < 16) stUi(hd + i, 0);
  if (i < NLAYER * L) stUi(done + i, 0);
}

__global__ void __launch_bounds__(NT, 1) kMega(P p) {
  __shared__ float hS[4][D];
  __shared__ float qS[4][D];
  __shared__ float xnS[D];
  __shared__ float oS[D];
  __shared__ float fS[512];
  __shared__ float padS[4096];
  __shared__ float redS[8];
  __shared__ float sortS[L];
  __shared__ int cntS[NT + 1];
  int wg = blockIdx.x, t = threadIdx.x;
  int b = 0;
  int* cnt = p.barc;

  // ================= PHASE A: full pass, 4 rows/WG =================
  for (int i = 0; i < 4; ++i) {
    int row = wg + i * NWG;
    int tok = p.lat[row];
    if (t < D) hS[i][t] = p.emb[tok * D + t] + p.pos[row * D + t];
    __syncthreads();
    lnorm(p.ln1_s, p.ln1_b, hS[i], xnS, redS);
    qkvPub<false>(p, 0, row, 0, xnS, qS[i], padS);
  }
  barFull(cnt, b);
  for (int l = 0; l < NLAYER; ++l) {
    for (int i = 0; i < 4; ++i) {
      int row = wg + i * NWG;
      attnProjFFN(p, row, l, hS[i], qS[i], oS, xnS, fS, padS, redS);
      if (l < NLAYER - 1) {
        lnorm(p.ln1_s + (l+1)*D, p.ln1_b + (l+1)*D, hS[i], xnS, redS);
        qkvPub<false>(p, l + 1, row, 0, xnS, qS[i], padS);
      } else {
        headRow<false>(p, row, hS[i], xnS, redS, padS, oS);
      }
    }
    barFull(cnt, b);
  }

  // ================= log-likelihoods =================
  {
    int gid = wg * NT + t;
    if (gid < L) {
      float r[V];
#pragma unroll
      for (int v = 0; v < V; ++v) r[v] = p.logits[gid * V + v];
      float m = r[0];
#pragma unroll
      for (int v = 1; v < V; ++v) m = fmaxf(m, r[v]);
      float s = 0.f;
#pragma unroll
      for (int v = 0; v < V; ++v) s += expf(r[v] - m);
      p.ll_[gid] = r[p.lat[gid + 1]] - (m + logf(s));
    }
  }
  barFull(cnt, b);

  // ================= sort + quantile + heal list (WG 0) =================
  if (wg == 0) {
    sortS[t] = p.ll_[t];
    __syncthreads();
    for (int ksz = 2; ksz <= L; ksz <<= 1) {
      for (int j = ksz >> 1; j; j >>= 1) {
        int pr = t ^ j;
        if (pr > t) {
          bool up = ((t & ksz) == 0);
          float a = sortS[t], bb = sortS[pr];
          if ((a > bb) == up) { sortS[t] = bb; sortS[pr] = a; }
        }
        __syncthreads();
      }
    }
    if (t == 0) {
      double frac = 0.03 * 1023.0 - 30.0;  // 0.69
      redS[0] = (float)((double)sortS[30] + frac * ((double)sortS[31] - (double)sortS[30]));
    }
    __syncthreads();
    float val = redS[0];
    int cc = (p.ll_[t] < val) ? 1 : 0;
    cntS[t] = cc;
    __syncthreads();
    if (t == 0) {
      int run = 0;
      for (int i = 0; i < NT; ++i) { int c2 = cntS[i]; cntS[i] = run; run += c2; }
      cntS[NT] = run;
    }
    __syncthreads();
    if (cc && cntS[t] < 31) p.heal_row[cntS[t]] = t;
    __syncthreads();
    if (t == 0) {
      int c = cntS[NT]; if (c > 31) c = 31;
      p.heal_row[31] = c;
      stUi(p.heals_done, 1);
      if (c > 0) {
        int r0 = p.heal_row[0];
        int best = 0; float bv = p.logits[r0 * V];
        for (int v = 1; v < BOSX; ++v) {
          float x = p.logits[r0 * V + v];
          if (x > bv) { bv = x; best = v; }
        }
        stUi(&p.lat[r0 + 1], best);
      }
    }
  }
  barFull(cnt, b);  // inv: drops all phase-A K/V lines from every L2/L1

  // ================= HEAL: barrier-free row pipeline, cached K/V reads ======
  int c = p.heal_row[31];
  int split = (c > 0) ? (p.heal_row[0] + 1) : L;
  for (int r = split + wg; r < L; r += NWG) {
    int nh = 0, hk = -1;
    for (int j = 0; j < c; ++j) {
      nh += (p.heal_row[j] < r) ? 1 : 0;
      if (j >= 1 && p.heal_row[j] == r) hk = j;
    }
    if (t == 0) {
      while (ldUi(p.heals_done) < nh) __builtin_amdgcn_s_sleep(1);
      cntS[0] = ldUi(&p.lat[r]);
    }
    __syncthreads();
    int tok = cntS[0];
    if (t < D) hS[0][t] = p.emb[tok * D + t] + p.pos[r * D + t];
    __syncthreads();
    lnorm(p.ln1_s, p.ln1_b, hS[0], xnS, redS);
    qkvPub<true>(p, 0, r, split, xnS, qS[0], padS);
    for (int l = 0; l < NLAYER; ++l) {
      attnProjFFN(p, r, l, hS[0], qS[0], oS, xnS, fS, padS, redS);
      if (l < NLAYER - 1) {
        lnorm(p.ln1_s + (l+1)*D, p.ln1_b + (l+1)*D, hS[0], xnS, redS);
        qkvPub<true>(p, l + 1, r, split, xnS, qS[0], padS);
      } else {
        headRow<true>(p, r, hS[0], xnS, redS, padS, oS);
      }
    }
    if (hk >= 0 && t == 0) {
      int best = 0; float bv = oS[0];
      for (int v = 1; v < BOSX; ++v)
        if (oS[v] > bv) { bv = oS[v]; best = v; }
      stUi(&p.lat[r + 1], best);
      asm volatile("s_waitcnt vmcnt(0)" ::: "memory");
      stUi(p.heals_done, hk + 1);
    }
  }

  barFull(cnt, b);

  // ================= tokens out =================
  {
    int gid = wg * NT + t;
    if (gid < L) p.out_tok[gid] = (float)ldUi(&p.lat[gid + 1]);
  }
}

extern "C" void kernel_launch(void* const* d_in, const int* in_sizes, int n_in,
                              void* d_out, int out_size, void* d_ws, size_t ws_size,
                              hipStream_t stream) {
  P prm;
  prm.tokens = (const int*)d_in[0];
  prm.emb    = (const float*)d_in[1];
  prm.pos    = (const float*)d_in[2];
  prm.ln1_s  = (const float*)d_in[3];
  prm.ln1_b  = (const float*)d_in[4];
  prm.wqkv   = (const float*)d_in[5];
  prm.bqkv   = (const float*)d_in[6];
  prm.wo     = (const float*)d_in[7];
  prm.bo     = (const float*)d_in[8];
  prm.ln2_s  = (const float*)d_in[9];
  prm.ln2_b  = (const float*)d_in[10];
  prm.w1     = (const float*)d_in[11];
  prm.b1     = (const float*)d_in[12];
  prm.w2     = (const float*)d_in[13];
  prm.b2     = (const float*)d_in[14];
  prm.lnf_s  = (const float*)d_in[15];
  prm.lnf_b  = (const float*)d_in[16];
  prm.hw     = (const float*)d_in[17];
  prm.hb     = (const float*)d_in[18];

  float* ws = (float*)d_ws;
  prm.kc   = ws;                            // NLAYER*L*D
  prm.vc   = prm.kc + (size_t)NLAYER*L*D;   // NLAYER*L*D
  prm.ll_  = prm.vc + (size_t)NLAYER*L*D;   // L
  prm.lat        = (int*)(prm.ll_ + L);     // 1025 (pad 1032)
  prm.heal_row   = prm.lat + 1032;          // 32 ([31] = count)
  prm.barc       = prm.heal_row + 32;       // 64
  prm.done       = prm.barc + 64;           // NLAYER*L
  prm.heals_done = prm.done + NLAYER * L;   // 16

  prm.logits  = (float*)d_out;              // L*V
  prm.out_tok = prm.logits + L * V;         // L

  kInit<<<64, 256, 0, stream>>>(prm.tokens, prm.lat, prm.barc, prm.done, prm.heals_done);

  void* args[] = { &prm };
  (void)hipLaunchCooperativeKernel((const void*)kMega, dim3(NWG), dim3(NT), args, 0, stream);
}